// Round 1
// baseline (2492.867 us; speedup 1.0000x reference)
//
#include <hip/hip_runtime.h>
#include <math.h>

#define NB 16
#define NT 24
#define NH 112
#define NW 112
#define CIN 3
#define NF 32
#define HP 56
#define WP 56
#define ND (HP*WP*NF)   // 100352
#define LN_EPS 1e-3f

// Fused per-timestep kernel:
//   z = conv_stride2(x_t, Wk) + b + conv_stride1(h_{t-1}, Uk)
//   LSTM pointwise, write raw h_t into out[b,t,:], update c in ws.
// Block: (hp, b). 256 threads: f = tid&31, s = tid>>5 (8 wp slots),
// each thread covers wp = s + 8j (j=0..6) for all 4 gates.
__global__ __launch_bounds__(256, 2)
void lstm_step(const float* __restrict__ x,    // (B,T,H,W,CIN)
               const float* __restrict__ Wk,   // (3,3,CIN,128)
               const float* __restrict__ Uk,   // (3,3,F,128)
               const float* __restrict__ bias, // (128)
               float* __restrict__ out,        // (B,T,HP,WP,F) raw h then LN'd
               float* __restrict__ cbuf,       // (B,HP,WP,F)
               int t, int first)
{
    __shared__ float h_lds[3*58*32];    // rows hp-1..hp+1, wp_pad 0..57, c  (5568)
    __shared__ float x_lds[3*113*3];    // rows 2hp..2hp+2, col 0..112, c   (1017)
    __shared__ float wk_lds[27*32*4];   // [k][f][g]                        (3456)
    __shared__ float u_lds[32*32*4];    // per-tap [c][f][g]                (4096)

    const int tid = threadIdx.x;
    const int f  = tid & 31;
    const int s  = tid >> 5;
    const int hp = blockIdx.x;
    const int b  = blockIdx.y;

    // ---- stage x patch (zero-pad OOB) ----
    {
        const float* xt = x + (size_t)(b*NT + t) * (NH*NW*CIN);
        for (int idx = tid; idx < 3*113*3; idx += 256) {
            int dy  = idx / 339;
            int rem = idx - dy*339;
            int col = rem / 3;
            int c   = rem - col*3;
            int row = 2*hp + dy;
            float v = 0.f;
            if (row < NH && col < NW)
                v = xt[(row*NW + col)*CIN + c];
            x_lds[idx] = v;
        }
    }
    // ---- stage Wk as [k][f][g] ----
    for (int idx = tid; idx < 27*128; idx += 256) {
        int k  = idx >> 7;
        int n  = idx & 127;
        int g  = n >> 5;
        int ff = n & 31;
        wk_lds[(k*32 + ff)*4 + g] = Wk[idx];
    }
    // ---- stage h patch (float4, zero-pad boundary) ----
    if (!first) {
        const float* hprev = out + (size_t)(b*NT + (t-1)) * ND;
        for (int q = tid; q < 1392; q += 256) {   // 5568/4
            int flat = q*4;
            int dy  = flat / 1856;                // 58*32
            int rem = flat - dy*1856;
            int wpp = rem >> 5;
            int c0  = rem & 31;
            int row = hp - 1 + dy;
            int wg  = wpp - 1;
            float4 v = make_float4(0.f,0.f,0.f,0.f);
            if (row >= 0 && row < HP && wg >= 0 && wg < WP)
                v = *(const float4*)&hprev[(row*WP + wg)*NF + c0];
            *(float4*)&h_lds[flat] = v;
        }
    }
    __syncthreads();

    // ---- accumulators: acc[j] = (zi, zf, zc, zo) for wp = s + 8j ----
    float4 acc[7];
    {
        float b0 = bias[f], b1 = bias[f+32], b2 = bias[f+64], b3 = bias[f+96];
        #pragma unroll
        for (int j = 0; j < 7; j++) acc[j] = make_float4(b0,b1,b2,b3);
    }

    // ---- x path: 27 taps ----
    #pragma unroll
    for (int dy = 0; dy < 3; dy++)
    #pragma unroll
    for (int dx = 0; dx < 3; dx++)
    #pragma unroll
    for (int c = 0; c < 3; c++) {
        int k = (dy*3 + dx)*3 + c;
        float4 w = *(float4*)&wk_lds[(k*32 + f)*4];
        #pragma unroll
        for (int j = 0; j < 7; j++) {
            int wp = s + 8*j;
            float a = x_lds[(dy*113 + (2*wp + dx))*3 + c];
            acc[j].x += a*w.x; acc[j].y += a*w.y; acc[j].z += a*w.z; acc[j].w += a*w.w;
        }
    }

    // ---- h path: 9 taps, K=32 each, staged per tap ----
    if (!first) {
        for (int tap = 0; tap < 9; tap++) {
            // stage U[tap] as [c][f][g]
            for (int idx = tid; idx < 4096; idx += 256) {
                int c  = idx >> 7;
                int n  = idx & 127;
                int g  = n >> 5;
                int ff = n & 31;
                u_lds[(c*32 + ff)*4 + g] = Uk[(tap*32 + c)*128 + n];
            }
            __syncthreads();

            int dy = tap / 3, dx = tap - dy*3;
            int hbase = (dy*58 + s + dx)*32;   // + j*256 + c0
            #pragma unroll
            for (int c0 = 0; c0 < 32; c0 += 4) {
                float4 w0 = *(float4*)&u_lds[((c0+0)*32 + f)*4];
                float4 w1 = *(float4*)&u_lds[((c0+1)*32 + f)*4];
                float4 w2 = *(float4*)&u_lds[((c0+2)*32 + f)*4];
                float4 w3 = *(float4*)&u_lds[((c0+3)*32 + f)*4];
                #pragma unroll
                for (int j = 0; j < 7; j++) {
                    float4 a = *(float4*)&h_lds[hbase + j*256 + c0];
                    acc[j].x += a.x*w0.x; acc[j].y += a.x*w0.y; acc[j].z += a.x*w0.z; acc[j].w += a.x*w0.w;
                    acc[j].x += a.y*w1.x; acc[j].y += a.y*w1.y; acc[j].z += a.y*w1.z; acc[j].w += a.y*w1.w;
                    acc[j].x += a.z*w2.x; acc[j].y += a.z*w2.y; acc[j].z += a.z*w2.z; acc[j].w += a.z*w2.w;
                    acc[j].x += a.w*w3.x; acc[j].y += a.w*w3.y; acc[j].z += a.w*w3.z; acc[j].w += a.w*w3.w;
                }
            }
            __syncthreads();   // before next tap restages u_lds
        }
    }

    // ---- LSTM pointwise + writes ----
    {
        float* orow = out + (size_t)(b*NT + t) * ND;
        float* crow = cbuf + (size_t)b * ND;
        #pragma unroll
        for (int j = 0; j < 7; j++) {
            int wp = s + 8*j;
            int sp = (hp*WP + wp)*NF + f;
            float zi = acc[j].x, zf = acc[j].y, zc = acc[j].z, zo = acc[j].w;
            float ig = fminf(fmaxf(zi*0.2f + 0.5f, 0.f), 1.f);
            float fg = fminf(fmaxf(zf*0.2f + 0.5f, 0.f), 1.f);
            float og = fminf(fmaxf(zo*0.2f + 0.5f, 0.f), 1.f);
            float cprev = first ? 0.f : crow[sp];
            float cn = fg*cprev + ig*tanhf(zc);
            crow[sp] = cn;
            orow[sp] = og*tanhf(cn);
        }
    }
}

// In-place LayerNorm of each (b,t) row of length D.
__global__ __launch_bounds__(256)
void ln_kernel(float* __restrict__ out,
               const float* __restrict__ gamma,
               const float* __restrict__ beta)
{
    const int row = blockIdx.x;             // b*T + t
    float* y = out + (size_t)row * ND;
    const int tid = threadIdx.x;

    float sum = 0.f, sumsq = 0.f;
    for (int q = tid; q < ND/4; q += 256) {
        float4 v = *(float4*)&y[q*4];
        sum   += v.x + v.y + v.z + v.w;
        sumsq += v.x*v.x + v.y*v.y + v.z*v.z + v.w*v.w;
    }
    #pragma unroll
    for (int off = 32; off > 0; off >>= 1) {
        sum   += __shfl_down(sum, off);
        sumsq += __shfl_down(sumsq, off);
    }
    __shared__ float s1[4], s2[4];
    int wave = tid >> 6, lane = tid & 63;
    if (lane == 0) { s1[wave] = sum; s2[wave] = sumsq; }
    __syncthreads();
    if (tid == 0) {
        float a  = s1[0] + s1[1] + s1[2] + s1[3];
        float b2 = s2[0] + s2[1] + s2[2] + s2[3];
        float mu  = a / (float)ND;
        float var = b2 / (float)ND - mu*mu;
        s1[0] = mu;
        s2[0] = rsqrtf(var + LN_EPS);
    }
    __syncthreads();
    float mu = s1[0], rs = s2[0];
    for (int q = tid; q < ND/4; q += 256) {
        float4 v  = *(float4*)&y[q*4];
        float4 g  = *(const float4*)&gamma[q*4];
        float4 be = *(const float4*)&beta[q*4];
        v.x = (v.x - mu)*rs*g.x + be.x;
        v.y = (v.y - mu)*rs*g.y + be.y;
        v.z = (v.z - mu)*rs*g.z + be.z;
        v.w = (v.w - mu)*rs*g.w + be.w;
        *(float4*)&y[q*4] = v;
    }
}

extern "C" void kernel_launch(void* const* d_in, const int* in_sizes, int n_in,
                              void* d_out, int out_size, void* d_ws, size_t ws_size,
                              hipStream_t stream)
{
    const float* x     = (const float*)d_in[0];
    const float* Wk    = (const float*)d_in[1];
    const float* Uk    = (const float*)d_in[2];
    const float* bias  = (const float*)d_in[3];
    const float* gamma = (const float*)d_in[4];
    const float* beta  = (const float*)d_in[5];
    float* out  = (float*)d_out;
    float* cbuf = (float*)d_ws;   // B*D floats = 6.4 MB

    for (int t = 0; t < NT; t++) {
        hipLaunchKernelGGL(lstm_step, dim3(HP, NB), dim3(256), 0, stream,
                           x, Wk, Uk, bias, out, cbuf, t, (t == 0) ? 1 : 0);
    }
    hipLaunchKernelGGL(ln_kernel, dim3(NB*NT), dim3(256), 0, stream,
                       out, gamma, beta);
}

// Round 2
// 1147.675 us; speedup vs baseline: 2.1721x; 2.1721x over previous
//
#include <hip/hip_runtime.h>
#include <math.h>

#define NB 16
#define NT 24
#define NH 112
#define NW 112
#define HP 56
#define WP 56
#define NF 32
#define ND (HP*WP*NF)   // 100352
#define LN_EPS 1e-3f

typedef __attribute__((ext_vector_type(8))) short short8;
typedef __attribute__((ext_vector_type(4))) float floatx4;

__device__ __forceinline__ float tanh_fast(float x){
    // tanh(x) = 1 - 2/(exp(2x)+1); exact at +-inf, NaN-free for finite x
    float e = __expf(2.0f*x);
    return 1.0f - 2.0f*__builtin_amdgcn_rcpf(e + 1.0f);
}
__device__ __forceinline__ float hsig(float z){
    return fminf(fmaxf(z*0.2f + 0.5f, 0.0f), 1.0f);
}
__device__ __forceinline__ ushort f2bf(float v){  // fp32 -> bf16 bits, RNE
    unsigned u = __float_as_uint(v);
    return (ushort)((u + 0x7fffu + ((u >> 16) & 1u)) >> 16);
}

// One fused ConvLSTM timestep, bf16 MFMA implicit GEMM.
// grid (14, 16, 2) = (hp-quad, b, f-half); block 256 = 4 waves.
// Wave w handles hp row hpq*4+w: M=64 (wp 0..63, pad >=56), N=64 (4 gates x 16 f).
__global__ __launch_bounds__(256, 2)
void rec_step(const float* __restrict__ x,     // (B,T,112,112,3)
              const float* __restrict__ Wk,    // (3,3,3,128)
              const float* __restrict__ Uk,    // (3,3,32,128)
              const float* __restrict__ bias,  // (128)
              const ushort* __restrict__ hprev,// (B,56,56,32) bf16
              ushort* __restrict__ hnext,      // (B,56,56,32) bf16
              float* __restrict__ cbuf,        // (B,56,56,32) fp32
              float* __restrict__ out,         // (B,T,56,56,32) fp32
              int t, int first)
{
    __shared__ ushort u_lds[9*64*32];   // [tap][n'][k]  36864 B
    __shared__ ushort h_lds[6*66*32];   // rows hpq*4-1..+4, cols -1..64, c  25344 B
    __shared__ ushort x_lds[9*113*3];   // rows 8hpq..8hpq+8 (bf16)  6102 B
    __shared__ ushort wk_lds[64*32];    // [n'][k27pad32]  4096 B

    const int tid   = threadIdx.x;
    const int hpq   = blockIdx.x;
    const int b     = blockIdx.y;
    const int fhalf = blockIdx.z;
    const int lane  = tid & 63;
    const int w     = tid >> 6;       // wave id = local hp row
    const int col   = lane & 15;
    const int q     = lane >> 4;
    const int q8    = q * 8;
    const int f0    = fhalf * 16;

    // ---- stage x rows (zero-pad OOB; SAME stride-2 pads bottom/right only) ----
    {
        const float* xt = x + ((size_t)(b*NT + t))*(NH*NW*3);
        for (int e = tid; e < 9*113*3; e += 256){
            int row = e / 339;
            int rem = e - row*339;
            int cw  = rem / 3;
            int cc  = rem - cw*3;
            int rg  = 8*hpq + row;
            float v = 0.f;
            if (rg < NH && cw < NW) v = xt[(rg*NW + cw)*3 + cc];
            x_lds[e] = f2bf(v);
        }
    }
    // ---- stage Wk half: [n'][k], n' = g*16 + f'' ----
    for (int e = tid; e < 64*32; e += 256){
        int k = e & 31;
        int n = e >> 5;
        int gidx = (n >> 4)*32 + f0 + (n & 15);
        float v = (k < 27) ? Wk[k*128 + gidx] : 0.f;
        wk_lds[e] = f2bf(v);
    }
    if (!first){
        // ---- stage Uk half: [tap][n'][c] ----
        for (int e = tid; e < 9*64*32; e += 256){
            int c   = e & 31;
            int n   = (e >> 5) & 63;
            int tap = e >> 11;
            int gidx = (n >> 4)*32 + f0 + (n & 15);
            u_lds[e] = f2bf(Uk[(tap*32 + c)*128 + gidx]);
        }
        // ---- stage h patch (bf16, zero-pad) ----
        const ushort* hsrc = hprev + (size_t)b*ND;
        for (int e = tid; e < 6*66*4; e += 256){
            int cq   = e & 3;
            int rc   = e >> 2;
            int row  = rc / 66;
            int colh = rc - row*66;
            int rg = hpq*4 - 1 + row;
            int cg = colh - 1;
            uint4 v = make_uint4(0u,0u,0u,0u);
            if (rg >= 0 && rg < HP && cg >= 0 && cg < WP)
                v = *(const uint4*)&hsrc[(rg*WP + cg)*NF + cq*8];
            *(uint4*)&h_lds[(row*66 + colh)*32 + cq*8] = v;
        }
    }
    __syncthreads();

    // ---- accumulators, bias folded in ----
    floatx4 acc[4][4];
    #pragma unroll
    for (int g = 0; g < 4; g++){
        float bg = bias[g*32 + f0 + col];
        #pragma unroll
        for (int mt = 0; mt < 4; mt++)
            acc[mt][g] = (floatx4){bg, bg, bg, bg};
    }

    // ---- input conv as one K=32 MFMA step (k>=27 zero-padded) ----
    {
        short8 ax[4];
        #pragma unroll
        for (int mt = 0; mt < 4; mt++){
            int wp = mt*16 + col;
            short8 v;
            #pragma unroll
            for (int j = 0; j < 8; j++){
                int k = q8 + j;
                ushort bits = 0;
                if (k < 27){
                    int dy = k/9; int rr = k - dy*9; int dx = rr/3; int cc = rr - dx*3;
                    int xc = 2*wp + dx; if (xc > 112) xc = 112;   // pad wp: reads staged zero
                    bits = x_lds[((2*w + dy)*113 + xc)*3 + cc];
                }
                v[j] = (short)bits;
            }
            ax[mt] = v;
        }
        #pragma unroll
        for (int g = 0; g < 4; g++){
            short8 bx = *(const short8*)&wk_lds[(g*16 + col)*32 + q8];
            #pragma unroll
            for (int mt = 0; mt < 4; mt++)
                acc[mt][g] = __builtin_amdgcn_mfma_f32_16x16x32_bf16(ax[mt], bx, acc[mt][g], 0, 0, 0);
        }
    }

    // ---- 9 recurrent taps, K=32 each ----
    if (!first){
        #pragma unroll
        for (int tap = 0; tap < 9; tap++){
            int dy = tap / 3, dx = tap - dy*3;
            short8 a[4], bb[4];
            #pragma unroll
            for (int mt = 0; mt < 4; mt++)
                a[mt] = *(const short8*)&h_lds[((w + dy)*66 + mt*16 + col + dx)*32 + q8];
            #pragma unroll
            for (int g = 0; g < 4; g++)
                bb[g] = *(const short8*)&u_lds[(tap*64 + g*16 + col)*32 + q8];
            #pragma unroll
            for (int mt = 0; mt < 4; mt++)
                #pragma unroll
                for (int g = 0; g < 4; g++)
                    acc[mt][g] = __builtin_amdgcn_mfma_f32_16x16x32_bf16(a[mt], bb[g], acc[mt][g], 0, 0, 0);
        }
    }

    // ---- LSTM pointwise epilogue (all 4 gates live in this lane) ----
    {
        float*  orow = out  + ((size_t)(b*NT + t))*ND;
        float*  crow = cbuf + (size_t)b*ND;
        ushort* hrow = hnext + (size_t)b*ND;
        int hp_g = hpq*4 + w;
        int f    = f0 + col;
        #pragma unroll
        for (int mt = 0; mt < 4; mt++){
            #pragma unroll
            for (int reg = 0; reg < 4; reg++){
                int wp = mt*16 + q*4 + reg;     // C/D row = quad*4 + reg
                if (wp < WP){
                    size_t idx = (size_t)(hp_g*WP + wp)*NF + f;
                    float zi = acc[mt][0][reg];
                    float zf = acc[mt][1][reg];
                    float zc = acc[mt][2][reg];
                    float zo = acc[mt][3][reg];
                    float ig = hsig(zi), fg = hsig(zf), og = hsig(zo);
                    float cprev = first ? 0.f : crow[idx];
                    float cn = fg*cprev + ig*tanh_fast(zc);
                    crow[idx] = cn;
                    float h = og*tanh_fast(cn);
                    orow[idx] = h;
                    hrow[idx] = f2bf(h);
                }
            }
        }
    }
}

// In-place LayerNorm of each (b,t) row of length D.
__global__ __launch_bounds__(256)
void ln_kernel(float* __restrict__ out,
               const float* __restrict__ gamma,
               const float* __restrict__ beta)
{
    const int row = blockIdx.x;             // b*T + t
    float* y = out + (size_t)row * ND;
    const int tid = threadIdx.x;

    float sum = 0.f, sumsq = 0.f;
    for (int qq = tid; qq < ND/4; qq += 256) {
        float4 v = *(float4*)&y[qq*4];
        sum   += v.x + v.y + v.z + v.w;
        sumsq += v.x*v.x + v.y*v.y + v.z*v.z + v.w*v.w;
    }
    #pragma unroll
    for (int off = 32; off > 0; off >>= 1) {
        sum   += __shfl_down(sum, off);
        sumsq += __shfl_down(sumsq, off);
    }
    __shared__ float s1[4], s2[4];
    int wave = tid >> 6, lane = tid & 63;
    if (lane == 0) { s1[wave] = sum; s2[wave] = sumsq; }
    __syncthreads();
    if (tid == 0) {
        float a  = s1[0] + s1[1] + s1[2] + s1[3];
        float b2 = s2[0] + s2[1] + s2[2] + s2[3];
        float mu  = a / (float)ND;
        float var = b2 / (float)ND - mu*mu;
        s1[0] = mu;
        s2[0] = rsqrtf(var + LN_EPS);
    }
    __syncthreads();
    float mu = s1[0], rs = s2[0];
    for (int qq = tid; qq < ND/4; qq += 256) {
        float4 v  = *(float4*)&y[qq*4];
        float4 g  = *(const float4*)&gamma[qq*4];
        float4 be = *(const float4*)&beta[qq*4];
        v.x = (v.x - mu)*rs*g.x + be.x;
        v.y = (v.y - mu)*rs*g.y + be.y;
        v.z = (v.z - mu)*rs*g.z + be.z;
        v.w = (v.w - mu)*rs*g.w + be.w;
        *(float4*)&y[qq*4] = v;
    }
}

extern "C" void kernel_launch(void* const* d_in, const int* in_sizes, int n_in,
                              void* d_out, int out_size, void* d_ws, size_t ws_size,
                              hipStream_t stream)
{
    const float* x     = (const float*)d_in[0];
    const float* Wk    = (const float*)d_in[1];
    const float* Uk    = (const float*)d_in[2];
    const float* bias  = (const float*)d_in[3];
    const float* gamma = (const float*)d_in[4];
    const float* beta  = (const float*)d_in[5];
    float* out = (float*)d_out;

    // ws: c-state fp32 (6.42 MB) + two bf16 h ping-pong buffers (3.21 MB each)
    float*  cbuf  = (float*)d_ws;
    ushort* hbuf0 = (ushort*)((char*)d_ws + (size_t)NB*ND*sizeof(float));
    ushort* hbuf1 = hbuf0 + (size_t)NB*ND;

    for (int t = 0; t < NT; t++) {
        ushort* hn = (t & 1) ? hbuf1 : hbuf0;
        const ushort* hv = (t & 1) ? hbuf0 : hbuf1;  // unused (not dereferenced) at t=0
        hipLaunchKernelGGL(rec_step, dim3(14, NB, 2), dim3(256), 0, stream,
                           x, Wk, Uk, bias, hv, hn, cbuf, out, t, (t == 0) ? 1 : 0);
    }
    hipLaunchKernelGGL(ln_kernel, dim3(NB*NT), dim3(256), 0, stream,
                       out, gamma, beta);
}

// Round 3
// 776.021 us; speedup vs baseline: 3.2124x; 1.4789x over previous
//
#include <hip/hip_runtime.h>
#include <math.h>

#define NB 16
#define NT 24
#define NH 112
#define NW 112
#define HP 56
#define WP 56
#define NF 32
#define ND (HP*WP*NF)   // 100352
#define LN_EPS 1e-3f

typedef __attribute__((ext_vector_type(8))) short short8;
typedef __attribute__((ext_vector_type(4))) float floatx4;

__device__ __forceinline__ float tanh_fast(float x){
    float e = __expf(2.0f*x);
    return 1.0f - 2.0f*__builtin_amdgcn_rcpf(e + 1.0f);
}
__device__ __forceinline__ float hsig(float z){
    return fminf(fmaxf(z*0.2f + 0.5f, 0.0f), 1.0f);
}
__device__ __forceinline__ ushort f2bf(float v){  // fp32 -> bf16 bits, RNE
    unsigned u = __float_as_uint(v);
    return (ushort)((u + 0x7fffu + ((u >> 16) & 1u)) >> 16);
}

// One-time weight repack: Uk -> ubuf bf16 [fhalf][tap][n'][k32],
//                          Wk -> wkbuf bf16 [fhalf][n'][k27pad32]
__global__ __launch_bounds__(256)
void prep_kernel(const float* __restrict__ Uk, const float* __restrict__ Wk,
                 ushort* __restrict__ ubuf, ushort* __restrict__ wkbuf)
{
    int e = blockIdx.x * 256 + threadIdx.x;
    if (e < 2*9*64*32) {
        int k  = e & 31;
        int n  = (e >> 5) & 63;
        int ft = e >> 11;               // fh*9 + tap, 0..17
        int fh = ft / 9;
        int tap = ft - fh*9;
        float v = Uk[(tap*32 + k)*128 + (n >> 4)*32 + fh*16 + (n & 15)];
        ubuf[e] = f2bf(v);
    } else {
        int e2 = e - 2*9*64*32;
        if (e2 < 2*64*32) {
            int k  = e2 & 31;
            int n  = (e2 >> 5) & 63;
            int fh = e2 >> 11;
            float v = (k < 27) ? Wk[k*128 + (n >> 4)*32 + fh*16 + (n & 15)] : 0.f;
            wkbuf[e2] = f2bf(v);
        }
    }
}

// One fused ConvLSTM timestep, bf16 MFMA implicit GEMM.
// grid (14, 16, 2) = (hp-quad, b, f-half); block 256 = 4 waves.
// Wave w handles hp row hpq*4+w: M=64 (wp 0..63, pad >=56), N=64 (4 gates x 16 f).
// B-fragments come straight from pre-packed global bf16 (coalesced, L1/L2 resident).
__global__ __launch_bounds__(256, 3)
void rec_step(const float* __restrict__ x,      // (B,T,112,112,3)
              const ushort* __restrict__ ubuf,  // [2][9][64][32] bf16
              const ushort* __restrict__ wkbuf, // [2][64][32] bf16
              const float* __restrict__ bias,   // (128)
              const ushort* __restrict__ hprev, // (B,56,56,32) bf16
              ushort* __restrict__ hnext,       // (B,56,56,32) bf16
              float* __restrict__ cbuf,         // (B,56,56,32) fp32
              float* __restrict__ out,          // (B,T,56,56,32) fp32
              float* __restrict__ stats,        // (B*T, 2) {sum, sumsq}
              int t, int first)
{
    __shared__ ushort h_lds[6*66*32];   // rows hpq*4-1..+4, cols -1..64, c  25344 B
    __shared__ ushort x_lds[9*113*3];   // rows 8hpq..8hpq+8 (bf16)  6102 B

    const int tid   = threadIdx.x;
    const int hpq   = blockIdx.x;
    const int b     = blockIdx.y;
    const int fhalf = blockIdx.z;
    const int lane  = tid & 63;
    const int w     = tid >> 6;       // wave id = local hp row
    const int col   = lane & 15;
    const int q     = lane >> 4;
    const int q8    = q * 8;
    const int f0    = fhalf * 16;

    // ---- stage x rows (zero-pad OOB) ----
    {
        const float* xt = x + ((size_t)(b*NT + t))*(NH*NW*3);
        for (int e = tid; e < 9*113*3; e += 256){
            int row = e / 339;
            int rem = e - row*339;
            int cw  = rem / 3;
            int cc  = rem - cw*3;
            int rg  = 8*hpq + row;
            float v = 0.f;
            if (rg < NH && cw < NW) v = xt[(rg*NW + cw)*3 + cc];
            x_lds[e] = f2bf(v);
        }
    }
    // ---- stage h patch (bf16, zero-pad) ----
    if (!first){
        const ushort* hsrc = hprev + (size_t)b*ND;
        for (int e = tid; e < 6*66*4; e += 256){
            int cq   = e & 3;
            int rc   = e >> 2;
            int row  = rc / 66;
            int colh = rc - row*66;
            int rg = hpq*4 - 1 + row;
            int cg = colh - 1;
            uint4 v = make_uint4(0u,0u,0u,0u);
            if (rg >= 0 && rg < HP && cg >= 0 && cg < WP)
                v = *(const uint4*)&hsrc[(rg*WP + cg)*NF + cq*8];
            *(uint4*)&h_lds[(row*66 + colh)*32 + cq*8] = v;
        }
    }
    __syncthreads();

    // ---- accumulators, bias folded in ----
    floatx4 acc[4][4];
    #pragma unroll
    for (int g = 0; g < 4; g++){
        float bg = bias[g*32 + f0 + col];
        #pragma unroll
        for (int mt = 0; mt < 4; mt++)
            acc[mt][g] = (floatx4){bg, bg, bg, bg};
    }

    // ---- input conv as one K=32 MFMA step (k>=27 zero-padded) ----
    {
        const ushort* wkb = wkbuf + fhalf*64*32;
        short8 ax[4];
        #pragma unroll
        for (int mt = 0; mt < 4; mt++){
            int wp = mt*16 + col;
            short8 v;
            #pragma unroll
            for (int j = 0; j < 8; j++){
                int k = q8 + j;
                ushort bits = 0;
                if (k < 27){
                    int dy = k/9; int rr = k - dy*9; int dx = rr/3; int cc = rr - dx*3;
                    int xc = 2*wp + dx; if (xc > 112) xc = 112;
                    bits = x_lds[((2*w + dy)*113 + xc)*3 + cc];
                }
                v[j] = (short)bits;
            }
            ax[mt] = v;
        }
        #pragma unroll
        for (int g = 0; g < 4; g++){
            short8 bx = *(const short8*)&wkb[(g*16 + col)*32 + q8];
            #pragma unroll
            for (int mt = 0; mt < 4; mt++)
                acc[mt][g] = __builtin_amdgcn_mfma_f32_16x16x32_bf16(ax[mt], bx, acc[mt][g], 0, 0, 0);
        }
    }

    // ---- 9 recurrent taps, K=32 each; B-frags from global bf16 ----
    if (!first){
        const ushort* ub = ubuf + (size_t)fhalf*9*64*32;
        #pragma unroll
        for (int tap = 0; tap < 9; tap++){
            int dy = tap / 3, dx = tap - dy*3;
            short8 a[4], bb[4];
            #pragma unroll
            for (int g = 0; g < 4; g++)
                bb[g] = *(const short8*)&ub[(tap*64 + g*16 + col)*32 + q8];
            #pragma unroll
            for (int mt = 0; mt < 4; mt++)
                a[mt] = *(const short8*)&h_lds[((w + dy)*66 + mt*16 + col + dx)*32 + q8];
            #pragma unroll
            for (int mt = 0; mt < 4; mt++)
                #pragma unroll
                for (int g = 0; g < 4; g++)
                    acc[mt][g] = __builtin_amdgcn_mfma_f32_16x16x32_bf16(a[mt], bb[g], acc[mt][g], 0, 0, 0);
        }
    }

    // ---- LSTM pointwise epilogue + fused LN partial stats ----
    {
        float*  orow = out  + ((size_t)(b*NT + t))*ND;
        float*  crow = cbuf + (size_t)b*ND;
        ushort* hrow = hnext + (size_t)b*ND;
        int hp_g = hpq*4 + w;
        int f    = f0 + col;
        float lsum = 0.f, lss = 0.f;
        #pragma unroll
        for (int mt = 0; mt < 4; mt++){
            #pragma unroll
            for (int reg = 0; reg < 4; reg++){
                int wp = mt*16 + q*4 + reg;     // C/D row = quad*4 + reg
                if (wp < WP){
                    size_t idx = (size_t)(hp_g*WP + wp)*NF + f;
                    float zi = acc[mt][0][reg];
                    float zf = acc[mt][1][reg];
                    float zc = acc[mt][2][reg];
                    float zo = acc[mt][3][reg];
                    float ig = hsig(zi), fg = hsig(zf), og = hsig(zo);
                    float cprev = first ? 0.f : crow[idx];
                    float cn = fg*cprev + ig*tanh_fast(zc);
                    crow[idx] = cn;
                    float h = og*tanh_fast(cn);
                    orow[idx] = h;
                    hrow[idx] = f2bf(h);
                    lsum += h;
                    lss  += h*h;
                }
            }
        }
        // wave-reduce stats, one atomic pair per wave
        #pragma unroll
        for (int off = 32; off > 0; off >>= 1){
            lsum += __shfl_down(lsum, off);
            lss  += __shfl_down(lss, off);
        }
        if (lane == 0){
            float* st = stats + (size_t)(b*NT + t)*2;
            atomicAdd(st,     lsum);
            atomicAdd(st + 1, lss);
        }
    }
}

// Scale-only LayerNorm: stats precomputed by rec_step.
// grid (B*T, 8); each block normalizes 12544 elements of its row.
__global__ __launch_bounds__(256)
void ln_scale(float* __restrict__ out,
              const float* __restrict__ stats,
              const float* __restrict__ gamma,
              const float* __restrict__ beta)
{
    const int row   = blockIdx.x;
    const int chunk = blockIdx.y;
    const int tid   = threadIdx.x;
    float s  = stats[(size_t)row*2];
    float ss = stats[(size_t)row*2 + 1];
    float mu = s * (1.0f/(float)ND);
    float var = ss * (1.0f/(float)ND) - mu*mu;
    float rs = rsqrtf(var + LN_EPS);

    float* y = out + (size_t)row*ND + chunk*(ND/8);
    const float* g0 = gamma + chunk*(ND/8);
    const float* b0 = beta  + chunk*(ND/8);
    for (int qq = tid; qq < ND/8/4; qq += 256){
        float4 v  = *(float4*)&y[qq*4];
        float4 g  = *(const float4*)&g0[qq*4];
        float4 be = *(const float4*)&b0[qq*4];
        v.x = (v.x - mu)*rs*g.x + be.x;
        v.y = (v.y - mu)*rs*g.y + be.y;
        v.z = (v.z - mu)*rs*g.z + be.z;
        v.w = (v.w - mu)*rs*g.w + be.w;
        *(float4*)&y[qq*4] = v;
    }
}

extern "C" void kernel_launch(void* const* d_in, const int* in_sizes, int n_in,
                              void* d_out, int out_size, void* d_ws, size_t ws_size,
                              hipStream_t stream)
{
    const float* x     = (const float*)d_in[0];
    const float* Wk    = (const float*)d_in[1];
    const float* Uk    = (const float*)d_in[2];
    const float* bias  = (const float*)d_in[3];
    const float* gamma = (const float*)d_in[4];
    const float* beta  = (const float*)d_in[5];
    float* out = (float*)d_out;

    // ws layout:
    //   cbuf   fp32  NB*ND            (6.42 MB)
    //   hbuf0  bf16  NB*ND            (3.21 MB)
    //   hbuf1  bf16  NB*ND            (3.21 MB)
    //   ubuf   bf16  2*9*64*32        (73728 B)
    //   wkbuf  bf16  2*64*32          (8192 B)
    //   stats  fp32  NB*NT*2          (3072 B)
    char* p = (char*)d_ws;
    float*  cbuf  = (float*)p;                 p += (size_t)NB*ND*4;
    ushort* hbuf0 = (ushort*)p;                p += (size_t)NB*ND*2;
    ushort* hbuf1 = (ushort*)p;                p += (size_t)NB*ND*2;
    ushort* ubuf  = (ushort*)p;                p += (size_t)2*9*64*32*2;
    ushort* wkbuf = (ushort*)p;                p += (size_t)2*64*32*2;
    float*  stats = (float*)p;

    hipMemsetAsync(stats, 0, (size_t)NB*NT*2*4, stream);
    hipLaunchKernelGGL(prep_kernel, dim3((2*9*64*32 + 2*64*32 + 255)/256), dim3(256), 0, stream,
                       Uk, Wk, ubuf, wkbuf);

    for (int t = 0; t < NT; t++) {
        ushort* hn = (t & 1) ? hbuf1 : hbuf0;
        const ushort* hv = (t & 1) ? hbuf0 : hbuf1;  // unused at t=0
        hipLaunchKernelGGL(rec_step, dim3(14, NB, 2), dim3(256), 0, stream,
                           x, ubuf, wkbuf, bias, hv, hn, cbuf, out, stats,
                           t, (t == 0) ? 1 : 0);
    }
    hipLaunchKernelGGL(ln_scale, dim3(NB*NT, 8), dim3(256), 0, stream,
                       out, stats, gamma, beta);
}